// Round 16
// baseline (154.693 us; speedup 1.0000x reference)
//
#include <hip/hip_runtime.h>
#include <math.h>

// TopK router via split-bf16 MFMA: logits = x @ W^T, top-2 + softmax.
// x = xh + xl (bf16 RTNE split via v_cvt_pk_bf16_f32), W preconverted to
// ws (h/l bf16) by wprep. logits = xh*wh + xh*wl + xl*wh (fp32 MFMA acc).
//
// Round-16: 4 independent barrier domains per CU.
// grid 1024 (4 blocks/CU), 256 thr = 4 waves, TOK=16, CK=128.
// Wave = kw (K32 window 0..3), all 64 experts: acc[4] (16 VGPR).
// r15's lockstep diagnosis: phase 6600 cyc vs 3200 component-max; with
// only 2 barrier domains/CU the B-load L2 latency + barrier skew can't be
// filled. 4 phase-shifted blocks/CU fill each other's stalls.
// Carried over unchanged: period-4 named x register sets, nodrain
// barriers (lgkmcnt only), XOR-swizzled double-buffered A LDS,
// B (W h/l) direct global (L2-hot), cvt_pk h/l split.

typedef float f32x4 __attribute__((ext_vector_type(4)));
typedef short bf16x8 __attribute__((ext_vector_type(8)));
typedef unsigned int u32;

#define NE 64
#define TOK 16
#define CK 128
#define THREADS 256
#define LDE 68

__device__ __forceinline__ u32 cvtpk(float lo, float hi) {
  u32 r;
  asm("v_cvt_pk_bf16_f32 %0, %1, %2" : "=v"(r) : "v"(lo), "v"(hi));
  return r;
}
__device__ __forceinline__ float asf(u32 u) {
  return __builtin_bit_cast(float, u);
}
// 8 f32 -> packed bf16 high (hp) and low-residual (lp); residual exact.
__device__ __forceinline__ void cvt8(const f32x4 a, const f32x4 b,
                                     uint4& hp, uint4& lp) {
  hp.x = cvtpk(a.x, a.y);
  hp.y = cvtpk(a.z, a.w);
  hp.z = cvtpk(b.x, b.y);
  hp.w = cvtpk(b.z, b.w);
  lp.x = cvtpk(a.x - asf(hp.x << 16), a.y - asf(hp.x & 0xFFFF0000u));
  lp.y = cvtpk(a.z - asf(hp.y << 16), a.w - asf(hp.y & 0xFFFF0000u));
  lp.z = cvtpk(b.x - asf(hp.z << 16), b.y - asf(hp.z & 0xFFFF0000u));
  lp.w = cvtpk(b.z - asf(hp.w << 16), b.w - asf(hp.w & 0xFFFF0000u));
}
// LDS byte address: 256B rows (128 bf16), 16B block XOR-swizzled by row
__device__ __forceinline__ int lds_addr(int base, int row, int blk) {
  return base + row * 256 + ((blk ^ (row & 7)) << 4);
}
// barrier that publishes LDS writes but does NOT drain vmem prefetches
__device__ __forceinline__ void barrier_nodrain() {
  asm volatile("s_waitcnt lgkmcnt(0)" ::: "memory");
  __builtin_amdgcn_s_barrier();
}

__global__ __launch_bounds__(256)
void wprep(const float* __restrict__ Wg, uint2* __restrict__ Who,
           uint2* __restrict__ Wlo) {
  const int i = blockIdx.x * 256 + threadIdx.x;   // f32x4 index (65536 total)
  const f32x4 v = *((const f32x4*)Wg + i);
  uint2 hp, lp;
  hp.x = cvtpk(v.x, v.y);
  hp.y = cvtpk(v.z, v.w);
  lp.x = cvtpk(v.x - asf(hp.x << 16), v.y - asf(hp.x & 0xFFFF0000u));
  lp.y = cvtpk(v.z - asf(hp.y << 16), v.w - asf(hp.y & 0xFFFF0000u));
  Who[i] = hp;
  Wlo[i] = lp;
}

__global__ __launch_bounds__(THREADS, 4)
void gemm_topk(const float* __restrict__ x, const u32* __restrict__ Whg,
               const u32* __restrict__ Wlg, float* __restrict__ out_probs,
               float* __restrict__ out_idx, int D) {
  __shared__ __align__(16) char smem[16384];
  // A staging: buf0 h@0 l@4096, buf1 h@8192 l@12288 (16 rows x 256B each)

  const int tid = threadIdx.x;
  const int w   = tid >> 6;        // wave id = kw (K32 window 0..3)
  const int l   = tid & 63;
  const int kw  = w;
  const int m0  = blockIdx.x * TOK;
  const int nCh = D / CK;          // 32 (>= 8, divisible by 4)
  const int Du  = D / 2;           // u32 per W row

  const int g   = l >> 4;          // k sub-group
  const int r16 = l & 15;

  // x staging map: thread -> (row=tid>>4, blk=tid&15); 8 f32 = one 16B blk
  const int xr = tid >> 4, xc = tid & 15;
  const float* xg = x + (size_t)(m0 + xr) * D + xc * 8;

  // B fragment bases (u32 units), L2-hot direct-global; tile n: +n*16*Du
  const u32* whb = Whg + (size_t)r16 * Du + kw * 16 + g * 4;
  const u32* wlb = Wlg + (size_t)r16 * Du + kw * 16 + g * 4;

  f32x4 acc[4];
#pragma unroll
  for (int n = 0; n < 4; ++n) acc[n] = (f32x4){0.f, 0.f, 0.f, 0.f};

  // four named x register sets (period-4 pipeline, no rotation movs)
  f32x4 xA0, xA1, xB0, xB1, xC0, xC1, xD0, xD1;

  // prologue: load chunks 0..4; convert+publish chunk 0
  {
    f32x4 xT0 = __builtin_nontemporal_load((const f32x4*)xg);
    f32x4 xT1 = __builtin_nontemporal_load((const f32x4*)(xg + 4));
    xA0 = __builtin_nontemporal_load((const f32x4*)(xg + 1 * CK));
    xA1 = __builtin_nontemporal_load((const f32x4*)(xg + 1 * CK + 4));
    xB0 = __builtin_nontemporal_load((const f32x4*)(xg + 2 * CK));
    xB1 = __builtin_nontemporal_load((const f32x4*)(xg + 2 * CK + 4));
    xC0 = __builtin_nontemporal_load((const f32x4*)(xg + 3 * CK));
    xC1 = __builtin_nontemporal_load((const f32x4*)(xg + 3 * CK + 4));
    xD0 = __builtin_nontemporal_load((const f32x4*)(xg + 4 * CK));
    xD1 = __builtin_nontemporal_load((const f32x4*)(xg + 4 * CK + 4));
    uint4 hp, lp;
    cvt8(xT0, xT1, hp, lp);
    *(uint4*)(smem + lds_addr(0,    xr, xc)) = hp;
    *(uint4*)(smem + lds_addr(4096, xr, xc)) = lp;
  }
  __syncthreads();

  // STEP(X, cc): convert X=x(cc+1)->buf; reload X<-x(cc+5); load B tiles;
  //              compute chunk cc (12 MFMA); nodrain barrier.
#define STEP(X0, X1, cc)                                                      \
  do {                                                                        \
    const size_t ko = (size_t)(cc) * (CK / 2);                                \
    if ((cc) + 1 < nCh) {                                                     \
      uint4 hp, lp;                                                           \
      cvt8(X0, X1, hp, lp);                                                   \
      const int wb = (((cc) + 1) & 1) * 8192;                                 \
      *(uint4*)(smem + lds_addr(wb,        xr, xc)) = hp;                     \
      *(uint4*)(smem + lds_addr(wb + 4096, xr, xc)) = lp;                     \
    }                                                                         \
    if ((cc) + 5 < nCh) {                                                     \
      const float* xn = xg + (size_t)((cc) + 5) * CK;                         \
      X0 = __builtin_nontemporal_load((const f32x4*)xn);                      \
      X1 = __builtin_nontemporal_load((const f32x4*)(xn + 4));                \
    }                                                                         \
    {                                                                         \
      const int rb  = ((cc) & 1) * 8192;                                      \
      const int blk = kw * 4 + g;                                             \
      const bf16x8 ah = *(const bf16x8*)(smem + lds_addr(rb,        r16, blk)); \
      const bf16x8 al = *(const bf16x8*)(smem + lds_addr(rb + 4096, r16, blk)); \
      _Pragma("unroll")                                                       \
      for (int n = 0; n < 4; ++n) {                                           \
        const bf16x8 bh = *(const bf16x8*)(whb + (size_t)n * 16 * Du + ko);   \
        const bf16x8 bl = *(const bf16x8*)(wlb + (size_t)n * 16 * Du + ko);   \
        acc[n] = __builtin_amdgcn_mfma_f32_16x16x32_bf16(ah, bh, acc[n], 0, 0, 0); \
        acc[n] = __builtin_amdgcn_mfma_f32_16x16x32_bf16(ah, bl, acc[n], 0, 0, 0); \
        acc[n] = __builtin_amdgcn_mfma_f32_16x16x32_bf16(al, bh, acc[n], 0, 0, 0); \
      }                                                                       \
    }                                                                         \
    barrier_nodrain();                                                        \
  } while (0)

  for (int c = 0; c < nCh; c += 4) {
    STEP(xA0, xA1, c);
    STEP(xB0, xB1, c + 1);
    STEP(xC0, xC1, c + 2);
    STEP(xD0, xD1, c + 3);
  }
#undef STEP

  __syncthreads();                  // all reads done before LDS reuse

  // ---- epilogue: reduce 4 k-windows, decode, top-2 ----
  float* R = (float*)smem;          // [4 waves][16 tr][64 lanes] = 16KB
#pragma unroll
  for (int n = 0; n < 4; ++n)
#pragma unroll
    for (int r = 0; r < 4; ++r)
      R[w * 1024 + (n * 4 + r) * 64 + l] = acc[n][r];
  __syncthreads();

  // 16 tok x 64 exp = 1024 values; 256 threads x 4
  float vals[4];
  int dsti[4];
#pragma unroll
  for (int i = 0; i < 4; ++i) {
    const int j = tid + i * THREADS;
    const int t = j >> 6, e = j & 63;
    const int nn = e >> 4;
    const int rr = t & 3;
    const int ll = (t >> 2) * 16 + (e & 15);
    float v = 0.f;
#pragma unroll
    for (int k = 0; k < 4; ++k)
      v += R[k * 1024 + (nn * 4 + rr) * 64 + ll];
    vals[i] = v;
    dsti[i] = t * LDE + e;
  }
  __syncthreads();                  // reads done before aliasing writes
  float* Lf = (float*)smem;         // [16][68]
#pragma unroll
  for (int i = 0; i < 4; ++i) Lf[dsti[i]] = vals[i];
  __syncthreads();

  if (tid < TOK) {
    const float* row = &Lf[tid * LDE];
    float b0 = -INFINITY, b1 = -INFINITY;
    int i0 = 0, i1 = 0;
#pragma unroll
    for (int e = 0; e < NE; ++e) {   // strict '>' = lowest index on ties
      const float val = row[e];
      if (val > b0) { b1 = b0; i1 = i0; b0 = val; i0 = e; }
      else if (val > b1) { b1 = val; i1 = e; }
    }
    const float e1  = expf(b1 - b0);
    const float inv = 1.f / (1.f + e1);
    const int tok = m0 + tid;
    out_probs[tok * 2 + 0] = inv;
    out_probs[tok * 2 + 1] = e1 * inv;
    out_idx[tok * 2 + 0] = (float)i0;
    out_idx[tok * 2 + 1] = (float)i1;
  }
}

// ---- fallback (round-6 fused VALU kernel) if ws is too small ----
#define FEW 8
#define FCK 64
#define FLDT 68
#define FTOK 64
__global__ __launch_bounds__(512, 2)
void router_fused(const float* __restrict__ x, const float* __restrict__ W,
                  float* __restrict__ out_probs, float* __restrict__ out_idx,
                  int D) {
  __shared__ float As[2][FTOK][FLDT];
  const int tid = threadIdx.x;
  const int w = __builtin_amdgcn_readfirstlane(tid >> 6);
  const int lane = tid & 63;
  const int m0 = blockIdx.x * FTOK;
  const int nCh = D / FCK;
  const float* xrow = x + (size_t)(m0 + lane) * D;
  const float* __restrict__ wbase = W + (size_t)(w * FEW) * D;
  float acc[FEW];
#pragma unroll
  for (int e = 0; e < FEW; ++e) acc[e] = 0.f;
  {
    const f32x4 a = *reinterpret_cast<const f32x4*>(xrow + 4 * w);
    const f32x4 b = *reinterpret_cast<const f32x4*>(xrow + 4 * (w + 8));
    *reinterpret_cast<f32x4*>(&As[0][lane][4 * w]) = a;
    *reinterpret_cast<f32x4*>(&As[0][lane][4 * (w + 8)]) = b;
  }
  __syncthreads();
  for (int c = 0; c < nCh; ++c) {
    const int buf = c & 1;
    f32x4 na, nb;
    const bool more = (c + 1 < nCh);
    if (more) {
      const float* xn = xrow + (size_t)(c + 1) * FCK;
      na = *reinterpret_cast<const f32x4*>(xn + 4 * w);
      nb = *reinterpret_cast<const f32x4*>(xn + 4 * (w + 8));
    }
    const float* __restrict__ wp = wbase + (size_t)c * FCK;
#pragma unroll 2
    for (int kk = 0; kk < FCK / 4; ++kk) {
      const f32x4 xvv = *reinterpret_cast<const f32x4*>(&As[buf][lane][kk * 4]);
#pragma unroll
      for (int e = 0; e < FEW; ++e) {
        const f32x4 wv = *reinterpret_cast<const f32x4*>(wp + (size_t)e * D + kk * 4);
        acc[e] = fmaf(xvv.x, wv.x, acc[e]);
        acc[e] = fmaf(xvv.y, wv.y, acc[e]);
        acc[e] = fmaf(xvv.z, wv.z, acc[e]);
        acc[e] = fmaf(xvv.w, wv.w, acc[e]);
      }
    }
    __syncthreads();
    if (more) {
      *reinterpret_cast<f32x4*>(&As[buf ^ 1][lane][4 * w]) = na;
      *reinterpret_cast<f32x4*>(&As[buf ^ 1][lane][4 * (w + 8)]) = nb;
    }
    __syncthreads();
  }
  float* L = &As[0][0][0];
  *reinterpret_cast<f32x4*>(&L[lane * FLDT + w * FEW + 0]) =
      (f32x4){acc[0], acc[1], acc[2], acc[3]};
  *reinterpret_cast<f32x4*>(&L[lane * FLDT + w * FEW + 4]) =
      (f32x4){acc[4], acc[5], acc[6], acc[7]};
  __syncthreads();
  if (tid < FTOK) {
    const float* row = &L[tid * FLDT];
    float b0 = -INFINITY, b1 = -INFINITY;
    int i0 = 0, i1 = 0;
#pragma unroll
    for (int e = 0; e < NE; ++e) {
      const float val = row[e];
      if (val > b0) { b1 = b0; i1 = i0; b0 = val; i0 = e; }
      else if (val > b1) { b1 = val; i1 = e; }
    }
    const float e1 = expf(b1 - b0);
    const float inv = 1.f / (1.f + e1);
    const int tok = m0 + tid;
    out_probs[tok * 2 + 0] = inv;
    out_probs[tok * 2 + 1] = e1 * inv;
    out_idx[tok * 2 + 0] = (float)i0;
    out_idx[tok * 2 + 1] = (float)i1;
  }
}

extern "C" void kernel_launch(void* const* d_in, const int* in_sizes, int n_in,
                              void* d_out, int out_size, void* d_ws, size_t ws_size,
                              hipStream_t stream) {
  const float* x = (const float*)d_in[0];
  const float* W = (const float*)d_in[1];

  const int E = 64;
  const int D = in_sizes[1] / E;            // 4096
  const int nTok = in_sizes[0] / D;         // 16384

  float* probs = (float*)d_out;
  float* idxo  = (float*)d_out + (size_t)nTok * 2;

  const size_t wBytes = (size_t)E * D * sizeof(short);   // 512 KB per half
  if (ws_size >= 2 * wBytes) {
    u32* Wh = (u32*)d_ws;
    u32* Wl = (u32*)((char*)d_ws + wBytes);
    hipLaunchKernelGGL(wprep, dim3((E * D / 4) / 256), dim3(256), 0, stream,
                       W, (uint2*)Wh, (uint2*)Wl);
    hipLaunchKernelGGL(gemm_topk, dim3(nTok / TOK), dim3(THREADS), 0, stream,
                       x, Wh, Wl, probs, idxo, D);
  } else {
    hipLaunchKernelGGL(router_fused, dim3(nTok / FTOK), dim3(512), 0, stream,
                       x, W, probs, idxo, D);
  }
}

// Round 17
// 104.143 us; speedup vs baseline: 1.4854x; 1.4854x over previous
//
#include <hip/hip_runtime.h>
#include <math.h>

// TopK router via split-bf16 MFMA: logits = x @ W^T, top-2 + softmax.
// x = xh + xl (bf16 RTNE split via v_cvt_pk_bf16_f32), W preconverted to
// ws (h/l bf16) by wprep. logits = xh*wh + xh*wl + xl*wh (fp32 MFMA acc).
//
// Round-17 = round-15 (best, 99.5us) + register double-buffered B.
// Two named B fragment sets (P/Q): STEP(cc) computes with the set loaded
// during STEP(cc-1) and issues B(cc+1) AFTER its MFMA cluster, so the
// ~250cy L2 round trip flies across the barrier under the next phase's
// cvt/ds_write/ds_read. Everything else identical to r15: unroll-4 loop,
// four named x sets, nodrain barriers, XOR-swizzled double-buffered A LDS,
// grid 512 (2 blocks/CU), 8 waves, 32 tok/block.

typedef float f32x4 __attribute__((ext_vector_type(4)));
typedef short bf16x8 __attribute__((ext_vector_type(8)));
typedef unsigned int u32;

#define NE 64
#define TOK 32
#define CK 128
#define THREADS 512
#define LDE 68

__device__ __forceinline__ u32 cvtpk(float lo, float hi) {
  u32 r;
  asm("v_cvt_pk_bf16_f32 %0, %1, %2" : "=v"(r) : "v"(lo), "v"(hi));
  return r;
}
__device__ __forceinline__ float asf(u32 u) {
  return __builtin_bit_cast(float, u);
}
// 8 f32 -> packed bf16 high (hp) and low-residual (lp); residual exact.
__device__ __forceinline__ void cvt8(const f32x4 a, const f32x4 b,
                                     uint4& hp, uint4& lp) {
  hp.x = cvtpk(a.x, a.y);
  hp.y = cvtpk(a.z, a.w);
  hp.z = cvtpk(b.x, b.y);
  hp.w = cvtpk(b.z, b.w);
  lp.x = cvtpk(a.x - asf(hp.x << 16), a.y - asf(hp.x & 0xFFFF0000u));
  lp.y = cvtpk(a.z - asf(hp.y << 16), a.w - asf(hp.y & 0xFFFF0000u));
  lp.z = cvtpk(b.x - asf(hp.z << 16), b.y - asf(hp.z & 0xFFFF0000u));
  lp.w = cvtpk(b.z - asf(hp.w << 16), b.w - asf(hp.w & 0xFFFF0000u));
}
// LDS byte address: 256B rows (128 bf16), 16B block XOR-swizzled by row
__device__ __forceinline__ int lds_addr(int base, int row, int blk) {
  return base + row * 256 + ((blk ^ (row & 7)) << 4);
}
// barrier that publishes LDS writes but does NOT drain vmem prefetches
__device__ __forceinline__ void barrier_nodrain() {
  asm volatile("s_waitcnt lgkmcnt(0)" ::: "memory");
  __builtin_amdgcn_s_barrier();
}

__global__ __launch_bounds__(256)
void wprep(const float* __restrict__ Wg, uint2* __restrict__ Who,
           uint2* __restrict__ Wlo) {
  const int i = blockIdx.x * 256 + threadIdx.x;   // f32x4 index (65536 total)
  const f32x4 v = *((const f32x4*)Wg + i);
  uint2 hp, lp;
  hp.x = cvtpk(v.x, v.y);
  hp.y = cvtpk(v.z, v.w);
  lp.x = cvtpk(v.x - asf(hp.x << 16), v.y - asf(hp.x & 0xFFFF0000u));
  lp.y = cvtpk(v.z - asf(hp.y << 16), v.w - asf(hp.y & 0xFFFF0000u));
  Who[i] = hp;
  Wlo[i] = lp;
}

__global__ __launch_bounds__(THREADS, 4)
void gemm_topk(const float* __restrict__ x, const u32* __restrict__ Whg,
               const u32* __restrict__ Wlg, float* __restrict__ out_probs,
               float* __restrict__ out_idx, int D) {
  __shared__ __align__(16) char smem[32768];
  // A staging: buf0 h@0 l@8192, buf1 h@16384 l@24576 (32 rows x 256B each)

  const int tid = threadIdx.x;
  const int w   = tid >> 6;
  const int l   = tid & 63;
  const int kw  = w & 3;           // K32 window within chunk
  const int eh  = w >> 2;          // expert half (0/1)
  const int m0  = blockIdx.x * TOK;
  const int nCh = D / CK;          // 32 (>= 8, divisible by 4)
  const int Du  = D / 2;           // u32 per W row

  const int g   = l >> 4;          // k sub-group
  const int r16 = l & 15;

  // x staging map: thread -> (row=tid>>4, blk=tid&15); 8 f32 = one 16B blk
  const int xr = tid >> 4, xc = tid & 15;
  const float* xg = x + (size_t)(m0 + xr) * D + xc * 8;

  // B fragment bases (u32 units), L2-hot direct-global
  const u32* wh0 = Whg + (size_t)(eh * 32 + 0  + r16) * Du + kw * 16 + g * 4;
  const u32* wh1 = Whg + (size_t)(eh * 32 + 16 + r16) * Du + kw * 16 + g * 4;
  const u32* wl0 = Wlg + (size_t)(eh * 32 + 0  + r16) * Du + kw * 16 + g * 4;
  const u32* wl1 = Wlg + (size_t)(eh * 32 + 16 + r16) * Du + kw * 16 + g * 4;

  f32x4 acc[2][2];
#pragma unroll
  for (int m = 0; m < 2; ++m)
#pragma unroll
    for (int n = 0; n < 2; ++n) acc[m][n] = (f32x4){0.f, 0.f, 0.f, 0.f};

  // four named x register sets (period-4 pipeline, no rotation movs)
  f32x4 xA0, xA1, xB0, xB1, xC0, xC1, xD0, xD1;
  // two named B register sets (period-2): consumed one phase after load
  bf16x8 pH0, pH1, pL0, pL1, qH0, qH1, qL0, qL1;

  // prologue: load chunks 0..4; convert+publish chunk 0; load B(0) -> P
  {
    f32x4 xT0 = __builtin_nontemporal_load((const f32x4*)xg);
    f32x4 xT1 = __builtin_nontemporal_load((const f32x4*)(xg + 4));
    xA0 = __builtin_nontemporal_load((const f32x4*)(xg + 1 * CK));
    xA1 = __builtin_nontemporal_load((const f32x4*)(xg + 1 * CK + 4));
    xB0 = __builtin_nontemporal_load((const f32x4*)(xg + 2 * CK));
    xB1 = __builtin_nontemporal_load((const f32x4*)(xg + 2 * CK + 4));
    xC0 = __builtin_nontemporal_load((const f32x4*)(xg + 3 * CK));
    xC1 = __builtin_nontemporal_load((const f32x4*)(xg + 3 * CK + 4));
    xD0 = __builtin_nontemporal_load((const f32x4*)(xg + 4 * CK));
    xD1 = __builtin_nontemporal_load((const f32x4*)(xg + 4 * CK + 4));
    pH0 = *(const bf16x8*)(wh0);
    pH1 = *(const bf16x8*)(wh1);
    pL0 = *(const bf16x8*)(wl0);
    pL1 = *(const bf16x8*)(wl1);
    uint4 hp, lp;
    cvt8(xT0, xT1, hp, lp);
    *(uint4*)(smem + lds_addr(0,    xr, xc)) = hp;
    *(uint4*)(smem + lds_addr(8192, xr, xc)) = lp;
  }
  __syncthreads();

  // STEP(X, CB, NB, cc): convert X=x(cc+1)->buf; reload X<-x(cc+5);
  //   compute chunk cc with CB (loaded last phase); issue NB<-B(cc+1)
  //   AFTER the MFMAs (flies across barrier); nodrain barrier.
#define STEP(X0, X1, CH0, CH1, CL0, CL1, NH0, NH1, NL0, NL1, cc)              \
  do {                                                                        \
    if ((cc) + 1 < nCh) {                                                     \
      uint4 hp, lp;                                                           \
      cvt8(X0, X1, hp, lp);                                                   \
      const int wb = (((cc) + 1) & 1) * 16384;                                \
      *(uint4*)(smem + lds_addr(wb,        xr, xc)) = hp;                     \
      *(uint4*)(smem + lds_addr(wb + 8192, xr, xc)) = lp;                     \
    }                                                                         \
    if ((cc) + 5 < nCh) {                                                     \
      const float* xn = xg + (size_t)((cc) + 5) * CK;                         \
      X0 = __builtin_nontemporal_load((const f32x4*)xn);                      \
      X1 = __builtin_nontemporal_load((const f32x4*)(xn + 4));                \
    }                                                                         \
    {                                                                         \
      const int rb  = ((cc) & 1) * 16384;                                     \
      const int blk = kw * 4 + g;                                             \
      const bf16x8 ah0 = *(const bf16x8*)(smem + lds_addr(rb,        r16, blk));      \
      const bf16x8 ah1 = *(const bf16x8*)(smem + lds_addr(rb,   16 + r16, blk));      \
      const bf16x8 al0 = *(const bf16x8*)(smem + lds_addr(rb + 8192,      r16, blk)); \
      const bf16x8 al1 = *(const bf16x8*)(smem + lds_addr(rb + 8192, 16 + r16, blk)); \
      acc[0][0] = __builtin_amdgcn_mfma_f32_16x16x32_bf16(ah0, CH0, acc[0][0], 0, 0, 0); \
      acc[0][0] = __builtin_amdgcn_mfma_f32_16x16x32_bf16(ah0, CL0, acc[0][0], 0, 0, 0); \
      acc[0][0] = __builtin_amdgcn_mfma_f32_16x16x32_bf16(al0, CH0, acc[0][0], 0, 0, 0); \
      acc[0][1] = __builtin_amdgcn_mfma_f32_16x16x32_bf16(ah0, CH1, acc[0][1], 0, 0, 0); \
      acc[0][1] = __builtin_amdgcn_mfma_f32_16x16x32_bf16(ah0, CL1, acc[0][1], 0, 0, 0); \
      acc[0][1] = __builtin_amdgcn_mfma_f32_16x16x32_bf16(al0, CH1, acc[0][1], 0, 0, 0); \
      acc[1][0] = __builtin_amdgcn_mfma_f32_16x16x32_bf16(ah1, CH0, acc[1][0], 0, 0, 0); \
      acc[1][0] = __builtin_amdgcn_mfma_f32_16x16x32_bf16(ah1, CL0, acc[1][0], 0, 0, 0); \
      acc[1][0] = __builtin_amdgcn_mfma_f32_16x16x32_bf16(al1, CH0, acc[1][0], 0, 0, 0); \
      acc[1][1] = __builtin_amdgcn_mfma_f32_16x16x32_bf16(ah1, CH1, acc[1][1], 0, 0, 0); \
      acc[1][1] = __builtin_amdgcn_mfma_f32_16x16x32_bf16(ah1, CL1, acc[1][1], 0, 0, 0); \
      acc[1][1] = __builtin_amdgcn_mfma_f32_16x16x32_bf16(al1, CH1, acc[1][1], 0, 0, 0); \
    }                                                                         \
    if ((cc) + 1 < nCh) {                                                     \
      const size_t kn = (size_t)((cc) + 1) * (CK / 2);                        \
      NH0 = *(const bf16x8*)(wh0 + kn);                                       \
      NH1 = *(const bf16x8*)(wh1 + kn);                                       \
      NL0 = *(const bf16x8*)(wl0 + kn);                                       \
      NL1 = *(const bf16x8*)(wl1 + kn);                                       \
    }                                                                         \
    barrier_nodrain();                                                        \
  } while (0)

  for (int c = 0; c < nCh; c += 4) {
    STEP(xA0, xA1, pH0, pH1, pL0, pL1, qH0, qH1, qL0, qL1, c);
    STEP(xB0, xB1, qH0, qH1, qL0, qL1, pH0, pH1, pL0, pL1, c + 1);
    STEP(xC0, xC1, pH0, pH1, pL0, pL1, qH0, qH1, qL0, qL1, c + 2);
    STEP(xD0, xD1, qH0, qH1, qL0, qL1, pH0, pH1, pL0, pL1, c + 3);
  }
#undef STEP

  // ---- epilogue: reduce 4 k-windows, decode, top-2 ----
  float* R = (float*)smem;          // [8 waves][16 tr][64 lanes] = 32KB
#pragma unroll
  for (int m = 0; m < 2; ++m)
#pragma unroll
    for (int n = 0; n < 2; ++n)
#pragma unroll
      for (int r = 0; r < 4; ++r)
        R[w * 1024 + ((m * 2 + n) * 4 + r) * 64 + l] = acc[m][n][r];
  __syncthreads();

  // 32 tok x 64 exp = 2048 values; 512 threads x 4
  float vals[4];
  int dsti[4];
#pragma unroll
  for (int i = 0; i < 4; ++i) {
    const int j = tid + i * THREADS;
    const int t = j >> 6, e = j & 63;
    const int mm = t >> 4, nn = (e >> 4) & 1, ee = e >> 5;
    const int rr = t & 3;
    const int ll = ((t & 15) >> 2) * 16 + (e & 15);
    float v = 0.f;
#pragma unroll
    for (int k = 0; k < 4; ++k)
      v += R[(ee * 4 + k) * 1024 + ((mm * 2 + nn) * 4 + rr) * 64 + ll];
    vals[i] = v;
    dsti[i] = t * LDE + e;
  }
  __syncthreads();                  // reads done before aliasing writes
  float* Lf = (float*)smem;         // [32][68]
#pragma unroll
  for (int i = 0; i < 4; ++i) Lf[dsti[i]] = vals[i];
  __syncthreads();

  if (tid < TOK) {
    const float* row = &Lf[tid * LDE];
    float b0 = -INFINITY, b1 = -INFINITY;
    int i0 = 0, i1 = 0;
#pragma unroll
    for (int e = 0; e < NE; ++e) {   // strict '>' = lowest index on ties
      const float val = row[e];
      if (val > b0) { b1 = b0; i1 = i0; b0 = val; i0 = e; }
      else if (val > b1) { b1 = val; i1 = e; }
    }
    const float e1  = expf(b1 - b0);
    const float inv = 1.f / (1.f + e1);
    const int tok = m0 + tid;
    out_probs[tok * 2 + 0] = inv;
    out_probs[tok * 2 + 1] = e1 * inv;
    out_idx[tok * 2 + 0] = (float)i0;
    out_idx[tok * 2 + 1] = (float)i1;
  }
}

// ---- fallback (round-6 fused VALU kernel) if ws is too small ----
#define FEW 8
#define FCK 64
#define FLDT 68
#define FTOK 64
__global__ __launch_bounds__(512, 2)
void router_fused(const float* __restrict__ x, const float* __restrict__ W,
                  float* __restrict__ out_probs, float* __restrict__ out_idx,
                  int D) {
  __shared__ float As[2][FTOK][FLDT];
  const int tid = threadIdx.x;
  const int w = __builtin_amdgcn_readfirstlane(tid >> 6);
  const int lane = tid & 63;
  const int m0 = blockIdx.x * FTOK;
  const int nCh = D / FCK;
  const float* xrow = x + (size_t)(m0 + lane) * D;
  const float* __restrict__ wbase = W + (size_t)(w * FEW) * D;
  float acc[FEW];
#pragma unroll
  for (int e = 0; e < FEW; ++e) acc[e] = 0.f;
  {
    const f32x4 a = *reinterpret_cast<const f32x4*>(xrow + 4 * w);
    const f32x4 b = *reinterpret_cast<const f32x4*>(xrow + 4 * (w + 8));
    *reinterpret_cast<f32x4*>(&As[0][lane][4 * w]) = a;
    *reinterpret_cast<f32x4*>(&As[0][lane][4 * (w + 8)]) = b;
  }
  __syncthreads();
  for (int c = 0; c < nCh; ++c) {
    const int buf = c & 1;
    f32x4 na, nb;
    const bool more = (c + 1 < nCh);
    if (more) {
      const float* xn = xrow + (size_t)(c + 1) * FCK;
      na = *reinterpret_cast<const f32x4*>(xn + 4 * w);
      nb = *reinterpret_cast<const f32x4*>(xn + 4 * (w + 8));
    }
    const float* __restrict__ wp = wbase + (size_t)c * FCK;
#pragma unroll 2
    for (int kk = 0; kk < FCK / 4; ++kk) {
      const f32x4 xvv = *reinterpret_cast<const f32x4*>(&As[buf][lane][kk * 4]);
#pragma unroll
      for (int e = 0; e < FEW; ++e) {
        const f32x4 wv = *reinterpret_cast<const f32x4*>(wp + (size_t)e * D + kk * 4);
        acc[e] = fmaf(xvv.x, wv.x, acc[e]);
        acc[e] = fmaf(xvv.y, wv.y, acc[e]);
        acc[e] = fmaf(xvv.z, wv.z, acc[e]);
        acc[e] = fmaf(xvv.w, wv.w, acc[e]);
      }
    }
    __syncthreads();
    if (more) {
      *reinterpret_cast<f32x4*>(&As[buf ^ 1][lane][4 * w]) = na;
      *reinterpret_cast<f32x4*>(&As[buf ^ 1][lane][4 * (w + 8)]) = nb;
    }
    __syncthreads();
  }
  float* L = &As[0][0][0];
  *reinterpret_cast<f32x4*>(&L[lane * FLDT + w * FEW + 0]) =
      (f32x4){acc[0], acc[1], acc[2], acc[3]};
  *reinterpret_cast<f32x4*>(&L[lane * FLDT + w * FEW + 4]) =
      (f32x4){acc[4], acc[5], acc[6], acc[7]};
  __syncthreads();
  if (tid < FTOK) {
    const float* row = &L[tid * FLDT];
    float b0 = -INFINITY, b1 = -INFINITY;
    int i0 = 0, i1 = 0;
#pragma unroll
    for (int e = 0; e < NE; ++e) {
      const float val = row[e];
      if (val > b0) { b1 = b0; i1 = i0; b0 = val; i0 = e; }
      else if (val > b1) { b1 = val; i1 = e; }
    }
    const float e1 = expf(b1 - b0);
    const float inv = 1.f / (1.f + e1);
    const int tok = m0 + tid;
    out_probs[tok * 2 + 0] = inv;
    out_probs[tok * 2 + 1] = e1 * inv;
    out_idx[tok * 2 + 0] = (float)i0;
    out_idx[tok * 2 + 1] = (float)i1;
  }
}

extern "C" void kernel_launch(void* const* d_in, const int* in_sizes, int n_in,
                              void* d_out, int out_size, void* d_ws, size_t ws_size,
                              hipStream_t stream) {
  const float* x = (const float*)d_in[0];
  const float* W = (const float*)d_in[1];

  const int E = 64;
  const int D = in_sizes[1] / E;            // 4096
  const int nTok = in_sizes[0] / D;         // 16384

  float* probs = (float*)d_out;
  float* idxo  = (float*)d_out + (size_t)nTok * 2;

  const size_t wBytes = (size_t)E * D * sizeof(short);   // 512 KB per half
  if (ws_size >= 2 * wBytes) {
    u32* Wh = (u32*)d_ws;
    u32* Wl = (u32*)((char*)d_ws + wBytes);
    hipLaunchKernelGGL(wprep, dim3((E * D / 4) / 256), dim3(256), 0, stream,
                       W, (uint2*)Wh, (uint2*)Wl);
    hipLaunchKernelGGL(gemm_topk, dim3(nTok / TOK), dim3(THREADS), 0, stream,
                       x, Wh, Wl, probs, idxo, D);
  } else {
    hipLaunchKernelGGL(router_fused, dim3(nTok / FTOK), dim3(512), 0, stream,
                       x, W, probs, idxo, D);
  }
}

// Round 18
// 90.205 us; speedup vs baseline: 1.7149x; 1.1545x over previous
//
#include <hip/hip_runtime.h>
#include <math.h>

// TopK router via split-bf16 MFMA: logits = x @ W^T, top-2 + softmax.
// x = xh + xl (bf16 RTNE split via v_cvt_pk_bf16_f32, consume-side),
// W preconverted to ws (h/l bf16) by wprep. logits = xh*wh+xh*wl+xl*wh.
//
// Round-18 = r15 geometry + global_load_lds fp32 A-staging.
// grid 512 (2 blocks/CU), 512 thr = 8 waves (kw 0..3, eh 0..1), TOK=32,
// CK=128. x staged fp32 HBM->LDS by DMA (2 gload16/thread/phase; zero
// staging VGPRs/VALU/ds_writes). Swizzle: 16B-granule XOR on the GLOBAL
// source (blk^(row&7)), linear LDS dest, same XOR on ds_read (rule #21).
// Per phase: B(c) loads FIRST, then gload(c+1) (newer -> B-waits keep the
// DMA in flight), ds_read fp32 + cvt8 + 12 MFMA, then vmcnt(0)+s_barrier
// (staging has ~a full phase in flight -> drain ~free; r14-proven pattern).

typedef float f32x4 __attribute__((ext_vector_type(4)));
typedef short bf16x8 __attribute__((ext_vector_type(8)));
typedef unsigned int u32;

#define NE 64
#define TOK 32
#define CK 128
#define THREADS 512
#define LDE 68

__device__ __forceinline__ u32 cvtpk(float lo, float hi) {
  u32 r;
  asm("v_cvt_pk_bf16_f32 %0, %1, %2" : "=v"(r) : "v"(lo), "v"(hi));
  return r;
}
__device__ __forceinline__ float asf(u32 u) {
  return __builtin_bit_cast(float, u);
}
// 8 f32 -> packed bf16 high (hp) and low-residual (lp); residual exact.
__device__ __forceinline__ void cvt8(const f32x4 a, const f32x4 b,
                                     uint4& hp, uint4& lp) {
  hp.x = cvtpk(a.x, a.y);
  hp.y = cvtpk(a.z, a.w);
  hp.z = cvtpk(b.x, b.y);
  hp.w = cvtpk(b.z, b.w);
  lp.x = cvtpk(a.x - asf(hp.x << 16), a.y - asf(hp.x & 0xFFFF0000u));
  lp.y = cvtpk(a.z - asf(hp.y << 16), a.w - asf(hp.y & 0xFFFF0000u));
  lp.z = cvtpk(b.x - asf(hp.z << 16), b.y - asf(hp.z & 0xFFFF0000u));
  lp.w = cvtpk(b.z - asf(hp.w << 16), b.w - asf(hp.w & 0xFFFF0000u));
}
// direct HBM->LDS, 16B per lane; LDS dest = wave-uniform base + lane*16
__device__ __forceinline__ void gload16(const void* gsrc, void* ldst) {
  __builtin_amdgcn_global_load_lds(
      (const __attribute__((address_space(1))) void*)gsrc,
      (__attribute__((address_space(3))) void*)ldst, 16, 0, 0);
}

__global__ __launch_bounds__(256)
void wprep(const float* __restrict__ Wg, uint2* __restrict__ Who,
           uint2* __restrict__ Wlo) {
  const int i = blockIdx.x * 256 + threadIdx.x;   // f32x4 index (65536 total)
  const f32x4 v = *((const f32x4*)Wg + i);
  uint2 hp, lp;
  hp.x = cvtpk(v.x, v.y);
  hp.y = cvtpk(v.z, v.w);
  lp.x = cvtpk(v.x - asf(hp.x << 16), v.y - asf(hp.x & 0xFFFF0000u));
  lp.y = cvtpk(v.z - asf(hp.y << 16), v.w - asf(hp.y & 0xFFFF0000u));
  Who[i] = hp;
  Wlo[i] = lp;
}

__global__ __launch_bounds__(THREADS, 4)
void gemm_topk(const float* __restrict__ x, const u32* __restrict__ Whg,
               const u32* __restrict__ Wlg, float* __restrict__ out_probs,
               float* __restrict__ out_idx, int D) {
  // main loop: 2 fp32 x-buffers of 16KB (32 rows x 512B); epilogue: R 32KB
  __shared__ __align__(16) char smem[32768];

  const int tid = threadIdx.x;
  const int w   = tid >> 6;
  const int l   = tid & 63;
  const int kw  = w & 3;           // K32 window within chunk
  const int eh  = w >> 2;          // expert half (0/1)
  const int m0  = blockIdx.x * TOK;
  const int nCh = D / CK;          // 32
  const int Du  = D / 2;           // u32 per W row

  const int g   = l >> 4;          // k sub-group
  const int r16 = l & 15;

  // ---- staging map: wave w covers rows {2w,2w+1} and {16+2w,16+2w+1}.
  // LDS dest linear (base + lane*16); GLOBAL source block pre-swizzled.
  const int rowA = 2 * w + (l >> 5);          // first 8KB half: rows 0..15
  const int rowB = 16 + rowA;                 // second half: rows 16..31
  const int bA   = (l & 31) ^ (rowA & 7);
  const int bB   = (l & 31) ^ (rowB & 7);
  const float* gA = x + (size_t)(m0 + rowA) * D + bA * 4;
  const float* gB = x + (size_t)(m0 + rowB) * D + bB * 4;

  // ---- B fragment bases (u32 units), L2-hot direct-global
  const u32* wh0 = Whg + (size_t)(eh * 32 + 0  + r16) * Du + kw * 16 + g * 4;
  const u32* wh1 = Whg + (size_t)(eh * 32 + 16 + r16) * Du + kw * 16 + g * 4;
  const u32* wl0 = Wlg + (size_t)(eh * 32 + 0  + r16) * Du + kw * 16 + g * 4;
  const u32* wl1 = Wlg + (size_t)(eh * 32 + 16 + r16) * Du + kw * 16 + g * 4;

  // ---- A read offsets (swizzled, 16B granule): tile m row = m*16+r16,
  // 16B blocks {c0, c0+1} with c0 = kw*8 + g*2  (f32 k-index kw*32+g*8)
  const int c0 = kw * 8 + g * 2;
  const int a00 = r16 * 512        + ((c0     ^ (r16 & 7)) << 4);
  const int a01 = r16 * 512        + (((c0+1) ^ (r16 & 7)) << 4);
  const int r1  = 16 + r16;
  const int a10 = r1 * 512         + ((c0     ^ (r1 & 7)) << 4);
  const int a11 = r1 * 512         + (((c0+1) ^ (r1 & 7)) << 4);

  f32x4 acc[2][2];
#pragma unroll
  for (int m = 0; m < 2; ++m)
#pragma unroll
    for (int n = 0; n < 2; ++n) acc[m][n] = (f32x4){0.f, 0.f, 0.f, 0.f};

  // prologue: stage chunk 0 into buf0
  gload16(gA, smem + w * 1024);
  gload16(gB, smem + 8192 + w * 1024);
  asm volatile("s_waitcnt vmcnt(0)\n\ts_barrier" ::: "memory");

  for (int c = 0; c < nCh; ++c) {
    const int rb = (c & 1) * 16384;
    const int wb = rb ^ 16384;

    // B(c) first (so compiler B-waits do NOT drain the newer DMA ops)
    const size_t ko = (size_t)c * (CK / 2);
    const bf16x8 bh0 = *(const bf16x8*)(wh0 + ko);
    const bf16x8 bh1 = *(const bf16x8*)(wh1 + ko);
    const bf16x8 bl0 = *(const bf16x8*)(wl0 + ko);
    const bf16x8 bl1 = *(const bf16x8*)(wl1 + ko);

    // DMA-stage chunk c+1 (in flight across the whole phase)
    if (c + 1 < nCh) {
      const float* nA = gA + (size_t)(c + 1) * CK;
      const float* nB = gB + (size_t)(c + 1) * CK;
      gload16(nA, smem + wb + w * 1024);
      gload16(nB, smem + wb + 8192 + w * 1024);
    }

    // A fragments: fp32 from LDS, cvt to bf16 h/l in-register
    const f32x4 t00 = *(const f32x4*)(smem + rb + a00);
    const f32x4 t01 = *(const f32x4*)(smem + rb + a01);
    const f32x4 t10 = *(const f32x4*)(smem + rb + a10);
    const f32x4 t11 = *(const f32x4*)(smem + rb + a11);
    uint4 hp0, lp0, hp1, lp1;
    cvt8(t00, t01, hp0, lp0);
    cvt8(t10, t11, hp1, lp1);
    const bf16x8 ah0 = __builtin_bit_cast(bf16x8, hp0);
    const bf16x8 al0 = __builtin_bit_cast(bf16x8, lp0);
    const bf16x8 ah1 = __builtin_bit_cast(bf16x8, hp1);
    const bf16x8 al1 = __builtin_bit_cast(bf16x8, lp1);

    acc[0][0] = __builtin_amdgcn_mfma_f32_16x16x32_bf16(ah0, bh0, acc[0][0], 0, 0, 0);
    acc[0][0] = __builtin_amdgcn_mfma_f32_16x16x32_bf16(ah0, bl0, acc[0][0], 0, 0, 0);
    acc[0][0] = __builtin_amdgcn_mfma_f32_16x16x32_bf16(al0, bh0, acc[0][0], 0, 0, 0);
    acc[0][1] = __builtin_amdgcn_mfma_f32_16x16x32_bf16(ah0, bh1, acc[0][1], 0, 0, 0);
    acc[0][1] = __builtin_amdgcn_mfma_f32_16x16x32_bf16(ah0, bl1, acc[0][1], 0, 0, 0);
    acc[0][1] = __builtin_amdgcn_mfma_f32_16x16x32_bf16(al0, bh1, acc[0][1], 0, 0, 0);
    acc[1][0] = __builtin_amdgcn_mfma_f32_16x16x32_bf16(ah1, bh0, acc[1][0], 0, 0, 0);
    acc[1][0] = __builtin_amdgcn_mfma_f32_16x16x32_bf16(ah1, bl0, acc[1][0], 0, 0, 0);
    acc[1][0] = __builtin_amdgcn_mfma_f32_16x16x32_bf16(al1, bh0, acc[1][0], 0, 0, 0);
    acc[1][1] = __builtin_amdgcn_mfma_f32_16x16x32_bf16(ah1, bh1, acc[1][1], 0, 0, 0);
    acc[1][1] = __builtin_amdgcn_mfma_f32_16x16x32_bf16(ah1, bl1, acc[1][1], 0, 0, 0);
    acc[1][1] = __builtin_amdgcn_mfma_f32_16x16x32_bf16(al1, bh1, acc[1][1], 0, 0, 0);

    // publish staged chunk; DMA had ~a full phase in flight -> near-free
    asm volatile("s_waitcnt vmcnt(0) lgkmcnt(0)\n\ts_barrier" ::: "memory");
  }

  __syncthreads();                  // settle before LDS reuse

  // ---- epilogue: reduce 4 k-windows, decode, top-2 ----
  float* R = (float*)smem;          // [8 waves][16 tr][64 lanes] = 32KB
#pragma unroll
  for (int m = 0; m < 2; ++m)
#pragma unroll
    for (int n = 0; n < 2; ++n)
#pragma unroll
      for (int r = 0; r < 4; ++r)
        R[w * 1024 + ((m * 2 + n) * 4 + r) * 64 + l] = acc[m][n][r];
  __syncthreads();

  // 32 tok x 64 exp = 2048 values; 512 threads x 4
  float vals[4];
  int dsti[4];
#pragma unroll
  for (int i = 0; i < 4; ++i) {
    const int j = tid + i * THREADS;
    const int t = j >> 6, e = j & 63;
    const int mm = t >> 4, nn = (e >> 4) & 1, ee = e >> 5;
    const int rr = t & 3;
    const int ll = ((t & 15) >> 2) * 16 + (e & 15);
    float v = 0.f;
#pragma unroll
    for (int k = 0; k < 4; ++k)
      v += R[(ee * 4 + k) * 1024 + ((mm * 2 + nn) * 4 + rr) * 64 + ll];
    vals[i] = v;
    dsti[i] = t * LDE + e;
  }
  __syncthreads();                  // reads done before aliasing writes
  float* Lf = (float*)smem;         // [32][68]
#pragma unroll
  for (int i = 0; i < 4; ++i) Lf[dsti[i]] = vals[i];
  __syncthreads();

  if (tid < TOK) {
    const float* row = &Lf[tid * LDE];
    float b0 = -INFINITY, b1 = -INFINITY;
    int i0 = 0, i1 = 0;
#pragma unroll
    for (int e = 0; e < NE; ++e) {   // strict '>' = lowest index on ties
      const float val = row[e];
      if (val > b0) { b1 = b0; i1 = i0; b0 = val; i0 = e; }
      else if (val > b1) { b1 = val; i1 = e; }
    }
    const float e1  = expf(b1 - b0);
    const float inv = 1.f / (1.f + e1);
    const int tok = m0 + tid;
    out_probs[tok * 2 + 0] = inv;
    out_probs[tok * 2 + 1] = e1 * inv;
    out_idx[tok * 2 + 0] = (float)i0;
    out_idx[tok * 2 + 1] = (float)i1;
  }
}

// ---- fallback (round-6 fused VALU kernel) if ws is too small ----
#define FEW 8
#define FCK 64
#define FLDT 68
#define FTOK 64
__global__ __launch_bounds__(512, 2)
void router_fused(const float* __restrict__ x, const float* __restrict__ W,
                  float* __restrict__ out_probs, float* __restrict__ out_idx,
                  int D) {
  __shared__ float As[2][FTOK][FLDT];
  const int tid = threadIdx.x;
  const int w = __builtin_amdgcn_readfirstlane(tid >> 6);
  const int lane = tid & 63;
  const int m0 = blockIdx.x * FTOK;
  const int nCh = D / FCK;
  const float* xrow = x + (size_t)(m0 + lane) * D;
  const float* __restrict__ wbase = W + (size_t)(w * FEW) * D;
  float acc[FEW];
#pragma unroll
  for (int e = 0; e < FEW; ++e) acc[e] = 0.f;
  {
    const f32x4 a = *reinterpret_cast<const f32x4*>(xrow + 4 * w);
    const f32x4 b = *reinterpret_cast<const f32x4*>(xrow + 4 * (w + 8));
    *reinterpret_cast<f32x4*>(&As[0][lane][4 * w]) = a;
    *reinterpret_cast<f32x4*>(&As[0][lane][4 * (w + 8)]) = b;
  }
  __syncthreads();
  for (int c = 0; c < nCh; ++c) {
    const int buf = c & 1;
    f32x4 na, nb;
    const bool more = (c + 1 < nCh);
    if (more) {
      const float* xn = xrow + (size_t)(c + 1) * FCK;
      na = *reinterpret_cast<const f32x4*>(xn + 4 * w);
      nb = *reinterpret_cast<const f32x4*>(xn + 4 * (w + 8));
    }
    const float* __restrict__ wp = wbase + (size_t)c * FCK;
#pragma unroll 2
    for (int kk = 0; kk < FCK / 4; ++kk) {
      const f32x4 xvv = *reinterpret_cast<const f32x4*>(&As[buf][lane][kk * 4]);
#pragma unroll
      for (int e = 0; e < FEW; ++e) {
        const f32x4 wv = *reinterpret_cast<const f32x4*>(wp + (size_t)e * D + kk * 4);
        acc[e] = fmaf(xvv.x, wv.x, acc[e]);
        acc[e] = fmaf(xvv.y, wv.y, acc[e]);
        acc[e] = fmaf(xvv.z, wv.z, acc[e]);
        acc[e] = fmaf(xvv.w, wv.w, acc[e]);
      }
    }
    __syncthreads();
    if (more) {
      *reinterpret_cast<f32x4*>(&As[buf ^ 1][lane][4 * w]) = na;
      *reinterpret_cast<f32x4*>(&As[buf ^ 1][lane][4 * (w + 8)]) = nb;
    }
    __syncthreads();
  }
  float* L = &As[0][0][0];
  *reinterpret_cast<f32x4*>(&L[lane * FLDT + w * FEW + 0]) =
      (f32x4){acc[0], acc[1], acc[2], acc[3]};
  *reinterpret_cast<f32x4*>(&L[lane * FLDT + w * FEW + 4]) =
      (f32x4){acc[4], acc[5], acc[6], acc[7]};
  __syncthreads();
  if (tid < FTOK) {
    const float* row = &L[tid * FLDT];
    float b0 = -INFINITY, b1 = -INFINITY;
    int i0 = 0, i1 = 0;
#pragma unroll
    for (int e = 0; e < NE; ++e) {
      const float val = row[e];
      if (val > b0) { b1 = b0; i1 = i0; b0 = val; i0 = e; }
      else if (val > b1) { b1 = val; i1 = e; }
    }
    const float e1 = expf(b1 - b0);
    const float inv = 1.f / (1.f + e1);
    const int tok = m0 + tid;
    out_probs[tok * 2 + 0] = inv;
    out_probs[tok * 2 + 1] = e1 * inv;
    out_idx[tok * 2 + 0] = (float)i0;
    out_idx[tok * 2 + 1] = (float)i1;
  }
}

extern "C" void kernel_launch(void* const* d_in, const int* in_sizes, int n_in,
                              void* d_out, int out_size, void* d_ws, size_t ws_size,
                              hipStream_t stream) {
  const float* x = (const float*)d_in[0];
  const float* W = (const float*)d_in[1];

  const int E = 64;
  const int D = in_sizes[1] / E;            // 4096
  const int nTok = in_sizes[0] / D;         // 16384

  float* probs = (float*)d_out;
  float* idxo  = (float*)d_out + (size_t)nTok * 2;

  const size_t wBytes = (size_t)E * D * sizeof(short);   // 512 KB per half
  if (ws_size >= 2 * wBytes) {
    u32* Wh = (u32*)d_ws;
    u32* Wl = (u32*)((char*)d_ws + wBytes);
    hipLaunchKernelGGL(wprep, dim3((E * D / 4) / 256), dim3(256), 0, stream,
                       W, (uint2*)Wh, (uint2*)Wl);
    hipLaunchKernelGGL(gemm_topk, dim3(nTok / TOK), dim3(THREADS), 0, stream,
                       x, Wh, Wl, probs, idxo, D);
  } else {
    hipLaunchKernelGGL(router_fused, dim3(nTok / FTOK), dim3(512), 0, stream,
                       x, W, probs, idxo, D);
  }
}

// Round 19
// 85.143 us; speedup vs baseline: 1.8169x; 1.0594x over previous
//
#include <hip/hip_runtime.h>
#include <math.h>

// TopK router via split-bf16 MFMA: logits = x @ W^T, top-2 + softmax.
// x = xh + xl (bf16 RTNE split via v_cvt_pk_bf16_f32, consume-side),
// W preconverted to ws (h/l bf16) by wprep. logits = xh*wh+xh*wl+xl*wh.
//
// Round-19 = r18 + T4 counted-wait pipeline (3 LDS buffers, depth-2 DMA).
// Stage chunk c+2 during phase c. Issue order per phase: B(c) loads, THEN
// DMA(c+2). vmem retires IN ORDER, so the compiler's natural vmcnt wait
// for B(c) (leaves only the 2 newest DMA ops outstanding) transitively
// retires DMA(c+1) -> the end-of-phase barrier is a PLAIN s_barrier
// (no vmcnt drain, no lgkm: loop has no ds_writes). DMA in flight ~2 full
// phases >> HBM latency. grid 512 (2 blocks/CU), 8 waves, TOK=32, CK=128,
// swizzled-source gload16, B (W h/l) direct global (L2-hot).

typedef float f32x4 __attribute__((ext_vector_type(4)));
typedef short bf16x8 __attribute__((ext_vector_type(8)));
typedef unsigned int u32;

#define NE 64
#define TOK 32
#define CK 128
#define THREADS 512
#define LDE 68

__device__ __forceinline__ u32 cvtpk(float lo, float hi) {
  u32 r;
  asm("v_cvt_pk_bf16_f32 %0, %1, %2" : "=v"(r) : "v"(lo), "v"(hi));
  return r;
}
__device__ __forceinline__ float asf(u32 u) {
  return __builtin_bit_cast(float, u);
}
// 8 f32 -> packed bf16 high (hp) and low-residual (lp); residual exact.
__device__ __forceinline__ void cvt8(const f32x4 a, const f32x4 b,
                                     uint4& hp, uint4& lp) {
  hp.x = cvtpk(a.x, a.y);
  hp.y = cvtpk(a.z, a.w);
  hp.z = cvtpk(b.x, b.y);
  hp.w = cvtpk(b.z, b.w);
  lp.x = cvtpk(a.x - asf(hp.x << 16), a.y - asf(hp.x & 0xFFFF0000u));
  lp.y = cvtpk(a.z - asf(hp.y << 16), a.w - asf(hp.y & 0xFFFF0000u));
  lp.z = cvtpk(b.x - asf(hp.z << 16), b.y - asf(hp.z & 0xFFFF0000u));
  lp.w = cvtpk(b.z - asf(hp.w << 16), b.w - asf(hp.w & 0xFFFF0000u));
}
// direct HBM->LDS, 16B per lane; LDS dest = wave-uniform base + lane*16
__device__ __forceinline__ void gload16(const void* gsrc, void* ldst) {
  __builtin_amdgcn_global_load_lds(
      (const __attribute__((address_space(1))) void*)gsrc,
      (__attribute__((address_space(3))) void*)ldst, 16, 0, 0);
}

__global__ __launch_bounds__(256)
void wprep(const float* __restrict__ Wg, uint2* __restrict__ Who,
           uint2* __restrict__ Wlo) {
  const int i = blockIdx.x * 256 + threadIdx.x;   // f32x4 index (65536 total)
  const f32x4 v = *((const f32x4*)Wg + i);
  uint2 hp, lp;
  hp.x = cvtpk(v.x, v.y);
  hp.y = cvtpk(v.z, v.w);
  lp.x = cvtpk(v.x - asf(hp.x << 16), v.y - asf(hp.x & 0xFFFF0000u));
  lp.y = cvtpk(v.z - asf(hp.y << 16), v.w - asf(hp.y & 0xFFFF0000u));
  Who[i] = hp;
  Wlo[i] = lp;
}

__global__ __launch_bounds__(THREADS, 2)
void gemm_topk(const float* __restrict__ x, const u32* __restrict__ Whg,
               const u32* __restrict__ Wlg, float* __restrict__ out_probs,
               float* __restrict__ out_idx, int D) {
  // 3 fp32 x-buffers of 16KB (32 rows x 512B); epilogue reuses first 32KB
  __shared__ __align__(16) char smem[49152];

  const int tid = threadIdx.x;
  const int w   = tid >> 6;
  const int l   = tid & 63;
  const int kw  = w & 3;           // K32 window within chunk
  const int eh  = w >> 2;          // expert half (0/1)
  const int m0  = blockIdx.x * TOK;
  const int nCh = D / CK;          // 32
  const int Du  = D / 2;           // u32 per W row

  const int g   = l >> 4;          // k sub-group
  const int r16 = l & 15;

  // ---- staging map: wave w covers rows {2w,2w+1} and {16+2w,16+2w+1}.
  // LDS dest linear (base + lane*16); GLOBAL source block pre-swizzled.
  const int rowA = 2 * w + (l >> 5);
  const int rowB = 16 + rowA;
  const int bA   = (l & 31) ^ (rowA & 7);
  const int bB   = (l & 31) ^ (rowB & 7);
  const float* gA = x + (size_t)(m0 + rowA) * D + bA * 4;
  const float* gB = x + (size_t)(m0 + rowB) * D + bB * 4;

  // ---- B fragment bases (u32 units), L2-hot direct-global
  const u32* wh0 = Whg + (size_t)(eh * 32 + 0  + r16) * Du + kw * 16 + g * 4;
  const u32* wh1 = Whg + (size_t)(eh * 32 + 16 + r16) * Du + kw * 16 + g * 4;
  const u32* wl0 = Wlg + (size_t)(eh * 32 + 0  + r16) * Du + kw * 16 + g * 4;
  const u32* wl1 = Wlg + (size_t)(eh * 32 + 16 + r16) * Du + kw * 16 + g * 4;

  // ---- A read offsets (swizzled, 16B granule)
  const int c0 = kw * 8 + g * 2;
  const int a00 = r16 * 512 + ((c0       ^ (r16 & 7)) << 4);
  const int a01 = r16 * 512 + (((c0 + 1) ^ (r16 & 7)) << 4);
  const int r1  = 16 + r16;
  const int a10 = r1 * 512 + ((c0       ^ (r1 & 7)) << 4);
  const int a11 = r1 * 512 + (((c0 + 1) ^ (r1 & 7)) << 4);

  f32x4 acc[2][2];
#pragma unroll
  for (int m = 0; m < 2; ++m)
#pragma unroll
    for (int n = 0; n < 2; ++n) acc[m][n] = (f32x4){0.f, 0.f, 0.f, 0.f};

  // prologue: DMA chunk 0 -> buf0, chunk 1 -> buf1; wait only chunk 0
  gload16(gA, smem + w * 1024);
  gload16(gB, smem + 8192 + w * 1024);
  if (nCh > 1) {
    gload16(gA + CK, smem + 16384 + w * 1024);
    gload16(gB + CK, smem + 16384 + 8192 + w * 1024);
  }
  asm volatile("s_waitcnt vmcnt(2)\n\ts_barrier" ::: "memory");

  for (int c = 0; c < nCh; ++c) {
    const int rb = (c % 3) * 16384;

    // B(c) first: issued AFTER DMA(c+1) (older) and BEFORE DMA(c+2).
    // In-order vmem retirement => the compiler's B-wait (vmcnt<=2)
    // transitively retires DMA(c+1) before any wave hits the barrier.
    const size_t ko = (size_t)c * (CK / 2);
    const bf16x8 bh0 = *(const bf16x8*)(wh0 + ko);
    const bf16x8 bh1 = *(const bf16x8*)(wh1 + ko);
    const bf16x8 bl0 = *(const bf16x8*)(wl0 + ko);
    const bf16x8 bl1 = *(const bf16x8*)(wl1 + ko);

    // DMA-stage chunk c+2 (in flight ~2 full phases)
    if (c + 2 < nCh) {
      const int wb = ((c + 2) % 3) * 16384;
      gload16(gA + (size_t)(c + 2) * CK, smem + wb + w * 1024);
      gload16(gB + (size_t)(c + 2) * CK, smem + wb + 8192 + w * 1024);
    }

    // A fragments: fp32 from LDS, cvt to bf16 h/l in-register
    const f32x4 t00 = *(const f32x4*)(smem + rb + a00);
    const f32x4 t01 = *(const f32x4*)(smem + rb + a01);
    const f32x4 t10 = *(const f32x4*)(smem + rb + a10);
    const f32x4 t11 = *(const f32x4*)(smem + rb + a11);
    uint4 hp0, lp0, hp1, lp1;
    cvt8(t00, t01, hp0, lp0);
    cvt8(t10, t11, hp1, lp1);
    const bf16x8 ah0 = __builtin_bit_cast(bf16x8, hp0);
    const bf16x8 al0 = __builtin_bit_cast(bf16x8, lp0);
    const bf16x8 ah1 = __builtin_bit_cast(bf16x8, hp1);
    const bf16x8 al1 = __builtin_bit_cast(bf16x8, lp1);

    acc[0][0] = __builtin_amdgcn_mfma_f32_16x16x32_bf16(ah0, bh0, acc[0][0], 0, 0, 0);
    acc[0][0] = __builtin_amdgcn_mfma_f32_16x16x32_bf16(ah0, bl0, acc[0][0], 0, 0, 0);
    acc[0][0] = __builtin_amdgcn_mfma_f32_16x16x32_bf16(al0, bh0, acc[0][0], 0, 0, 0);
    acc[0][1] = __builtin_amdgcn_mfma_f32_16x16x32_bf16(ah0, bh1, acc[0][1], 0, 0, 0);
    acc[0][1] = __builtin_amdgcn_mfma_f32_16x16x32_bf16(ah0, bl1, acc[0][1], 0, 0, 0);
    acc[0][1] = __builtin_amdgcn_mfma_f32_16x16x32_bf16(al0, bh1, acc[0][1], 0, 0, 0);
    acc[1][0] = __builtin_amdgcn_mfma_f32_16x16x32_bf16(ah1, bh0, acc[1][0], 0, 0, 0);
    acc[1][0] = __builtin_amdgcn_mfma_f32_16x16x32_bf16(ah1, bl0, acc[1][0], 0, 0, 0);
    acc[1][0] = __builtin_amdgcn_mfma_f32_16x16x32_bf16(al1, bh0, acc[1][0], 0, 0, 0);
    acc[1][1] = __builtin_amdgcn_mfma_f32_16x16x32_bf16(ah1, bh1, acc[1][1], 0, 0, 0);
    acc[1][1] = __builtin_amdgcn_mfma_f32_16x16x32_bf16(ah1, bl1, acc[1][1], 0, 0, 0);
    acc[1][1] = __builtin_amdgcn_mfma_f32_16x16x32_bf16(al1, bh1, acc[1][1], 0, 0, 0);

    // PLAIN barrier: no vmcnt drain (DMA stays in flight), no ds_writes.
    // 3 buffers + 1 barrier/phase bound wave skew to 1 phase -> safe.
    asm volatile("s_barrier" ::: "memory");
  }

  __syncthreads();                  // settle before LDS reuse

  // ---- epilogue: reduce 4 k-windows, decode, top-2 ----
  float* R = (float*)smem;          // [8 waves][16 tr][64 lanes] = 32KB
#pragma unroll
  for (int m = 0; m < 2; ++m)
#pragma unroll
    for (int n = 0; n < 2; ++n)
#pragma unroll
      for (int r = 0; r < 4; ++r)
        R[w * 1024 + ((m * 2 + n) * 4 + r) * 64 + l] = acc[m][n][r];
  __syncthreads();

  // 32 tok x 64 exp = 2048 values; 512 threads x 4
  float vals[4];
  int dsti[4];
#pragma unroll
  for (int i = 0; i < 4; ++i) {
    const int j = tid + i * THREADS;
    const int t = j >> 6, e = j & 63;
    const int mm = t >> 4, nn = (e >> 4) & 1, ee = e >> 5;
    const int rr = t & 3;
    const int ll = ((t & 15) >> 2) * 16 + (e & 15);
    float v = 0.f;
#pragma unroll
    for (int k = 0; k < 4; ++k)
      v += R[(ee * 4 + k) * 1024 + ((mm * 2 + nn) * 4 + rr) * 64 + ll];
    vals[i] = v;
    dsti[i] = t * LDE + e;
  }
  __syncthreads();                  // reads done before aliasing writes
  float* Lf = (float*)smem;         // [32][68]
#pragma unroll
  for (int i = 0; i < 4; ++i) Lf[dsti[i]] = vals[i];
  __syncthreads();

  if (tid < TOK) {
    const float* row = &Lf[tid * LDE];
    float b0 = -INFINITY, b1 = -INFINITY;
    int i0 = 0, i1 = 0;
#pragma unroll
    for (int e = 0; e < NE; ++e) {   // strict '>' = lowest index on ties
      const float val = row[e];
      if (val > b0) { b1 = b0; i1 = i0; b0 = val; i0 = e; }
      else if (val > b1) { b1 = val; i1 = e; }
    }
    const float e1  = expf(b1 - b0);
    const float inv = 1.f / (1.f + e1);
    const int tok = m0 + tid;
    out_probs[tok * 2 + 0] = inv;
    out_probs[tok * 2 + 1] = e1 * inv;
    out_idx[tok * 2 + 0] = (float)i0;
    out_idx[tok * 2 + 1] = (float)i1;
  }
}

// ---- fallback (round-6 fused VALU kernel) if ws is too small ----
#define FEW 8
#define FCK 64
#define FLDT 68
#define FTOK 64
__global__ __launch_bounds__(512, 2)
void router_fused(const float* __restrict__ x, const float* __restrict__ W,
                  float* __restrict__ out_probs, float* __restrict__ out_idx,
                  int D) {
  __shared__ float As[2][FTOK][FLDT];
  const int tid = threadIdx.x;
  const int w = __builtin_amdgcn_readfirstlane(tid >> 6);
  const int lane = tid & 63;
  const int m0 = blockIdx.x * FTOK;
  const int nCh = D / FCK;
  const float* xrow = x + (size_t)(m0 + lane) * D;
  const float* __restrict__ wbase = W + (size_t)(w * FEW) * D;
  float acc[FEW];
#pragma unroll
  for (int e = 0; e < FEW; ++e) acc[e] = 0.f;
  {
    const f32x4 a = *reinterpret_cast<const f32x4*>(xrow + 4 * w);
    const f32x4 b = *reinterpret_cast<const f32x4*>(xrow + 4 * (w + 8));
    *reinterpret_cast<f32x4*>(&As[0][lane][4 * w]) = a;
    *reinterpret_cast<f32x4*>(&As[0][lane][4 * (w + 8)]) = b;
  }
  __syncthreads();
  for (int c = 0; c < nCh; ++c) {
    const int buf = c & 1;
    f32x4 na, nb;
    const bool more = (c + 1 < nCh);
    if (more) {
      const float* xn = xrow + (size_t)(c + 1) * FCK;
      na = *reinterpret_cast<const f32x4*>(xn + 4 * w);
      nb = *reinterpret_cast<const f32x4*>(xn + 4 * (w + 8));
    }
    const float* __restrict__ wp = wbase + (size_t)c * FCK;
#pragma unroll 2
    for (int kk = 0; kk < FCK / 4; ++kk) {
      const f32x4 xvv = *reinterpret_cast<const f32x4*>(&As[buf][lane][kk * 4]);
#pragma unroll
      for (int e = 0; e < FEW; ++e) {
        const f32x4 wv = *reinterpret_cast<const f32x4*>(wp + (size_t)e * D + kk * 4);
        acc[e] = fmaf(xvv.x, wv.x, acc[e]);
        acc[e] = fmaf(xvv.y, wv.y, acc[e]);
        acc[e] = fmaf(xvv.z, wv.z, acc[e]);
        acc[e] = fmaf(xvv.w, wv.w, acc[e]);
      }
    }
    __syncthreads();
    if (more) {
      *reinterpret_cast<f32x4*>(&As[buf ^ 1][lane][4 * w]) = na;
      *reinterpret_cast<f32x4*>(&As[buf ^ 1][lane][4 * (w + 8)]) = nb;
    }
    __syncthreads();
  }
  float* L = &As[0][0][0];
  *reinterpret_cast<f32x4*>(&L[lane * FLDT + w * FEW + 0]) =
      (f32x4){acc[0], acc[1], acc[2], acc[3]};
  *reinterpret_cast<f32x4*>(&L[lane * FLDT + w * FEW + 4]) =
      (f32x4){acc[4], acc[5], acc[6], acc[7]};
  __syncthreads();
  if (tid < FTOK) {
    const float* row = &L[tid * FLDT];
    float b0 = -INFINITY, b1 = -INFINITY;
    int i0 = 0, i1 = 0;
#pragma unroll
    for (int e = 0; e < NE; ++e) {
      const float val = row[e];
      if (val > b0) { b1 = b0; i1 = i0; b0 = val; i0 = e; }
      else if (val > b1) { b1 = val; i1 = e; }
    }
    const float e1 = expf(b1 - b0);
    const float inv = 1.f / (1.f + e1);
    const int tok = m0 + tid;
    out_probs[tok * 2 + 0] = inv;
    out_probs[tok * 2 + 1] = e1 * inv;
    out_idx[tok * 2 + 0] = (float)i0;
    out_idx[tok * 2 + 1] = (float)i1;
  }
}

extern "C" void kernel_launch(void* const* d_in, const int* in_sizes, int n_in,
                              void* d_out, int out_size, void* d_ws, size_t ws_size,
                              hipStream_t stream) {
  const float* x = (const float*)d_in[0];
  const float* W = (const float*)d_in[1];

  const int E = 64;
  const int D = in_sizes[1] / E;            // 4096
  const int nTok = in_sizes[0] / D;         // 16384

  float* probs = (float*)d_out;
  float* idxo  = (float*)d_out + (size_t)nTok * 2;

  const size_t wBytes = (size_t)E * D * sizeof(short);   // 512 KB per half
  if (ws_size >= 2 * wBytes) {
    u32* Wh = (u32*)d_ws;
    u32* Wl = (u32*)((char*)d_ws + wBytes);
    hipLaunchKernelGGL(wprep, dim3((E * D / 4) / 256), dim3(256), 0, stream,
                       W, (uint2*)Wh, (uint2*)Wl);
    hipLaunchKernelGGL(gemm_topk, dim3(nTok / TOK), dim3(THREADS), 0, stream,
                       x, Wh, Wl, probs, idxo, D);
  } else {
    hipLaunchKernelGGL(router_fused, dim3(nTok / FTOK), dim3(512), 0, stream,
                       x, W, probs, idxo, D);
  }
}